// Round 1
// baseline (1530.648 us; speedup 1.0000x reference)
//
#include <hip/hip_runtime.h>
#include <hip/hip_bf16.h>

#define BATCH 16
#define CH 256
#define HH 128
#define WW 128
#define HWSZ (HH * WW)
#define NHEAD 8
#define DHEAD 32
#define LDST 40   // LDS row stride in bf16 elements (80B): 20 words, gcd(20,32)=4 -> bank-friendly

typedef __attribute__((ext_vector_type(8))) short bf16x8;
typedef __attribute__((ext_vector_type(4))) float f32x4;

__device__ __forceinline__ unsigned short f2b(float f) {
    unsigned u = __builtin_bit_cast(unsigned, f);
    u += 0x7fffu + ((u >> 16) & 1u);   // RNE
    return (unsigned short)(u >> 16);
}
__device__ __forceinline__ float b2f(unsigned short h) {
    unsigned u = ((unsigned)h) << 16;
    return __builtin_bit_cast(float, u);
}

// ---------------------------------------------------------------------------
// Kernel 1: channel projections  Y[b,o,p] = sum_c W[o,c] * X[b,c,p]  (bf16 out)
// BM=256 (all out channels), BN=64 px, BK=32, 4 waves each 64x64.
// ---------------------------------------------------------------------------
__global__ __launch_bounds__(256)
void proj_kernel(const float* __restrict__ q, const float* __restrict__ k,
                 const float* __restrict__ v,
                 const float* __restrict__ wq, const float* __restrict__ wk,
                 const float* __restrict__ wvw,
                 unsigned short* __restrict__ qh, unsigned short* __restrict__ kh,
                 unsigned short* __restrict__ vh)
{
    __shared__ unsigned short lA[256 * LDST];  // 20.0 KB  [o][k]
    __shared__ unsigned short lB[64 * LDST];   //  5.0 KB  [p][k] (transposed in staging)

    const int t = threadIdx.x;
    const int b = blockIdx.y;
    const int p0 = blockIdx.x * 64;

    const float* X; const float* Wm; unsigned short* Y;
    if (blockIdx.z == 0)      { X = q; Wm = wq;  Y = qh; }
    else if (blockIdx.z == 1) { X = k; Wm = wk;  Y = kh; }
    else                      { X = v; Wm = wvw; Y = vh; }
    X += (size_t)b * CH * HWSZ;
    Y += (size_t)b * CH * HWSZ;

    const int lane = t & 63;
    const int wid  = t >> 6;
    const int lrow = lane & 15;
    const int lkg  = lane >> 4;
    const int pB = t & 63;    // pixel this thread stages
    const int cg = t >> 6;    // k-subgroup (8 c's)

    f32x4 acc[4][4];
    const f32x4 zero = {0.f, 0.f, 0.f, 0.f};
#pragma unroll
    for (int m = 0; m < 4; ++m)
#pragma unroll
        for (int n = 0; n < 4; ++n) acc[m][n] = zero;

    for (int ks = 0; ks < 8; ++ks) {
        const int k0 = ks * 32;
        // --- stage A: W[t][k0..k0+32) fp32 -> bf16
        {
            const float4* wr = reinterpret_cast<const float4*>(Wm + t * 256 + k0);
#pragma unroll
            for (int i = 0; i < 8; ++i) {
                float4 f = wr[i];
                ushort4 hh;
                hh.x = f2b(f.x); hh.y = f2b(f.y); hh.z = f2b(f.z); hh.w = f2b(f.w);
                *reinterpret_cast<ushort4*>(&lA[t * LDST + i * 4]) = hh;
            }
        }
        // --- stage B transposed: lB[p][c] for c = k0+cg*8 .. +8
        {
            const float* xp = X + (size_t)(k0 + cg * 8) * HWSZ + p0 + pB;
            float fv[8];
#pragma unroll
            for (int i = 0; i < 8; ++i) fv[i] = xp[(size_t)i * HWSZ];
            ushort4 h0, h1;
            h0.x = f2b(fv[0]); h0.y = f2b(fv[1]); h0.z = f2b(fv[2]); h0.w = f2b(fv[3]);
            h1.x = f2b(fv[4]); h1.y = f2b(fv[5]); h1.z = f2b(fv[6]); h1.w = f2b(fv[7]);
            *reinterpret_cast<ushort4*>(&lB[pB * LDST + cg * 8])     = h0;
            *reinterpret_cast<ushort4*>(&lB[pB * LDST + cg * 8 + 4]) = h1;
        }
        __syncthreads();

        bf16x8 af[4], bfv[4];
#pragma unroll
        for (int m = 0; m < 4; ++m)
            af[m] = *reinterpret_cast<const bf16x8*>(&lA[(wid * 64 + m * 16 + lrow) * LDST + lkg * 8]);
#pragma unroll
        for (int n = 0; n < 4; ++n)
            bfv[n] = *reinterpret_cast<const bf16x8*>(&lB[(n * 16 + lrow) * LDST + lkg * 8]);
#pragma unroll
        for (int m = 0; m < 4; ++m)
#pragma unroll
            for (int n = 0; n < 4; ++n)
                acc[m][n] = __builtin_amdgcn_mfma_f32_16x16x32_bf16(af[m], bfv[n], acc[m][n], 0, 0, 0);
        __syncthreads();
    }

#pragma unroll
    for (int m = 0; m < 4; ++m)
#pragma unroll
        for (int n = 0; n < 4; ++n)
#pragma unroll
            for (int j = 0; j < 4; ++j) {
                int o = wid * 64 + m * 16 + (lane >> 4) * 4 + j;
                int p = p0 + n * 16 + (lane & 15);
                Y[(size_t)o * HWSZ + p] = f2b(acc[m][n][j]);
            }
}

// ---------------------------------------------------------------------------
// Kernel 2: local 5x5 window attention per (batch, head, 16x16 tile)
// ---------------------------------------------------------------------------
__global__ __launch_bounds__(256)
void attn_kernel(const unsigned short* __restrict__ qh, const unsigned short* __restrict__ kh,
                 const unsigned short* __restrict__ vh, unsigned short* __restrict__ ob)
{
    __shared__ unsigned short kt[400 * LDST];  // 31.25 KB, 20x20 halo x 32 d
    __shared__ unsigned short vt[400 * LDST];

    const int t = threadIdx.x;
    const int b = blockIdx.z, h = blockIdx.y;
    const int x0 = (blockIdx.x & 7) * 16, y0 = (blockIdx.x >> 3) * 16;
    const size_t base = ((size_t)b * CH + h * DHEAD) * HWSZ;

    // stage k/v halo, d-outer for coalescing; OOB -> 0 (matches zero-pad semantics)
    for (int d = 0; d < DHEAD; ++d) {
        const unsigned short* kp = kh + base + (size_t)d * HWSZ;
        const unsigned short* vp = vh + base + (size_t)d * HWSZ;
        for (int i = t; i < 400; i += 256) {
            int yy = y0 + i / 20 - 2;
            int xx = x0 + (i % 20) - 2;
            bool ok = ((unsigned)yy < HH) && ((unsigned)xx < WW);
            unsigned short kval = 0, vval = 0;
            if (ok) {
                int gi = yy * WW + xx;
                kval = kp[gi];
                vval = vp[gi];
            }
            kt[i * LDST + d] = kval;
            vt[i * LDST + d] = vval;
        }
    }

    const int px = t & 15, py = t >> 4;
    const int gx = x0 + px, gy = y0 + py;
    float qf[32];
#pragma unroll
    for (int d = 0; d < 32; ++d)
        qf[d] = b2f(qh[base + (size_t)d * HWSZ + gy * WW + gx]);
    __syncthreads();

    float ew[25];
#pragma unroll
    for (int wy = 0; wy < 5; ++wy)
#pragma unroll
        for (int wx = 0; wx < 5; ++wx) {
            int pos = (py + wy) * 20 + (px + wx);
            const unsigned short* kr = &kt[pos * LDST];
            float s = 0.f;
#pragma unroll
            for (int c = 0; c < 4; ++c) {
                bf16x8 kk = *reinterpret_cast<const bf16x8*>(kr + c * 8);
#pragma unroll
                for (int e = 0; e < 8; ++e)
                    s += qf[c * 8 + e] * b2f((unsigned short)kk[e]);
            }
            ew[wy * 5 + wx] = fmaxf(s, 0.f) * 0.17677669529663687f; // relu then /sqrt(32)
        }

    float mx = ew[0];
#pragma unroll
    for (int i = 1; i < 25; ++i) mx = fmaxf(mx, ew[i]);
    float sum = 0.f;
#pragma unroll
    for (int i = 0; i < 25; ++i) { ew[i] = __expf(ew[i] - mx); sum += ew[i]; }
    const float inv = 1.f / sum;

    float acc[32];
#pragma unroll
    for (int d = 0; d < 32; ++d) acc[d] = 0.f;
#pragma unroll
    for (int wy = 0; wy < 5; ++wy)
#pragma unroll
        for (int wx = 0; wx < 5; ++wx) {
            int pos = (py + wy) * 20 + (px + wx);
            float wgt = ew[wy * 5 + wx];
            const unsigned short* vr = &vt[pos * LDST];
#pragma unroll
            for (int c = 0; c < 4; ++c) {
                bf16x8 vv = *reinterpret_cast<const bf16x8*>(vr + c * 8);
#pragma unroll
                for (int e = 0; e < 8; ++e)
                    acc[c * 8 + e] += wgt * b2f((unsigned short)vv[e]);
            }
        }

#pragma unroll
    for (int d = 0; d < 32; ++d)
        ob[base + (size_t)d * HWSZ + gy * WW + gx] = f2b(acc[d] * inv);
}

// ---------------------------------------------------------------------------
// Kernel 3: o = wfc @ attn_out + residual, then LayerNorm over channels.
// Block owns ALL 256 out channels of its 64 pixels -> LN fully in-block.
// ---------------------------------------------------------------------------
__global__ __launch_bounds__(256)
void fcln_kernel(const unsigned short* __restrict__ ob, const float* __restrict__ wfc,
                 const float* __restrict__ qres, const float* __restrict__ lnw,
                 const float* __restrict__ lnb, float* __restrict__ out)
{
    __shared__ unsigned short lA[256 * LDST];
    __shared__ unsigned short lB[64 * LDST];
    __shared__ float lsum[4][64];
    __shared__ float lssq[4][64];

    const int t = threadIdx.x;
    const int b = blockIdx.y;
    const int p0 = blockIdx.x * 64;
    const unsigned short* Bsrc = ob + (size_t)b * CH * HWSZ;

    const int lane = t & 63;
    const int wid  = t >> 6;
    const int lrow = lane & 15;
    const int lkg  = lane >> 4;
    const int pB = t & 63;
    const int cg = t >> 6;

    f32x4 acc[4][4];
    const f32x4 zero = {0.f, 0.f, 0.f, 0.f};
#pragma unroll
    for (int m = 0; m < 4; ++m)
#pragma unroll
        for (int n = 0; n < 4; ++n) acc[m][n] = zero;

    for (int ks = 0; ks < 8; ++ks) {
        const int k0 = ks * 32;
        {
            const float4* wr = reinterpret_cast<const float4*>(wfc + t * 256 + k0);
#pragma unroll
            for (int i = 0; i < 8; ++i) {
                float4 f = wr[i];
                ushort4 hh;
                hh.x = f2b(f.x); hh.y = f2b(f.y); hh.z = f2b(f.z); hh.w = f2b(f.w);
                *reinterpret_cast<ushort4*>(&lA[t * LDST + i * 4]) = hh;
            }
        }
        {
            const unsigned short* xp = Bsrc + (size_t)(k0 + cg * 8) * HWSZ + p0 + pB;
            unsigned short uv[8];
#pragma unroll
            for (int i = 0; i < 8; ++i) uv[i] = xp[(size_t)i * HWSZ];
            ushort4 h0, h1;
            h0.x = uv[0]; h0.y = uv[1]; h0.z = uv[2]; h0.w = uv[3];
            h1.x = uv[4]; h1.y = uv[5]; h1.z = uv[6]; h1.w = uv[7];
            *reinterpret_cast<ushort4*>(&lB[pB * LDST + cg * 8])     = h0;
            *reinterpret_cast<ushort4*>(&lB[pB * LDST + cg * 8 + 4]) = h1;
        }
        __syncthreads();

        bf16x8 af[4], bfv[4];
#pragma unroll
        for (int m = 0; m < 4; ++m)
            af[m] = *reinterpret_cast<const bf16x8*>(&lA[(wid * 64 + m * 16 + lrow) * LDST + lkg * 8]);
#pragma unroll
        for (int n = 0; n < 4; ++n)
            bfv[n] = *reinterpret_cast<const bf16x8*>(&lB[(n * 16 + lrow) * LDST + lkg * 8]);
#pragma unroll
        for (int m = 0; m < 4; ++m)
#pragma unroll
            for (int n = 0; n < 4; ++n)
                acc[m][n] = __builtin_amdgcn_mfma_f32_16x16x32_bf16(af[m], bfv[n], acc[m][n], 0, 0, 0);
        __syncthreads();
    }

    // residual add (keep values in acc)
    const int lr = lane >> 4, lc = lane & 15;
    const float* qb = qres + (size_t)b * CH * HWSZ;
#pragma unroll
    for (int m = 0; m < 4; ++m)
#pragma unroll
        for (int n = 0; n < 4; ++n)
#pragma unroll
            for (int j = 0; j < 4; ++j) {
                int o = wid * 64 + m * 16 + lr * 4 + j;
                int p = p0 + n * 16 + lc;
                acc[m][n][j] += qb[(size_t)o * HWSZ + p];
            }

    // per-pixel LN partials: this wave holds channels [wid*64, wid*64+64)
    float s[4], s2[4];
#pragma unroll
    for (int n = 0; n < 4; ++n) {
        float a = 0.f, c2 = 0.f;
#pragma unroll
        for (int m = 0; m < 4; ++m)
#pragma unroll
            for (int j = 0; j < 4; ++j) {
                float x = acc[m][n][j];
                a += x; c2 += x * x;
            }
        a  += __shfl_xor(a, 16);  a  += __shfl_xor(a, 32);
        c2 += __shfl_xor(c2, 16); c2 += __shfl_xor(c2, 32);
        s[n] = a; s2[n] = c2;
    }
    if (lane < 16) {
#pragma unroll
        for (int n = 0; n < 4; ++n) {
            lsum[wid][n * 16 + lane] = s[n];
            lssq[wid][n * 16 + lane] = s2[n];
        }
    }
    __syncthreads();

    float mu[4], rs[4];
#pragma unroll
    for (int n = 0; n < 4; ++n) {
        int p = n * 16 + lc;
        float ts = lsum[0][p] + lsum[1][p] + lsum[2][p] + lsum[3][p];
        float tq = lssq[0][p] + lssq[1][p] + lssq[2][p] + lssq[3][p];
        float m_ = ts * (1.f / 256.f);
        float v_ = tq * (1.f / 256.f) - m_ * m_;
        mu[n] = m_;
        rs[n] = rsqrtf(v_ + 1e-6f);
    }

    float* op = out + (size_t)b * CH * HWSZ;
#pragma unroll
    for (int m = 0; m < 4; ++m)
#pragma unroll
        for (int j = 0; j < 4; ++j) {
            int o = wid * 64 + m * 16 + lr * 4 + j;
            float g = lnw[o], bb = lnb[o];
#pragma unroll
            for (int n = 0; n < 4; ++n) {
                int p = p0 + n * 16 + lc;
                op[(size_t)o * HWSZ + p] = (acc[m][n][j] - mu[n]) * rs[n] * g + bb;
            }
        }
}

extern "C" void kernel_launch(void* const* d_in, const int* in_sizes, int n_in,
                              void* d_out, int out_size, void* d_ws, size_t ws_size,
                              hipStream_t stream) {
    const float* q   = (const float*)d_in[0];
    const float* k   = (const float*)d_in[1];
    const float* v   = (const float*)d_in[2];
    const float* wq  = (const float*)d_in[3];
    const float* wk  = (const float*)d_in[4];
    const float* wvw = (const float*)d_in[5];
    const float* wfc = (const float*)d_in[6];
    const float* lnw = (const float*)d_in[7];
    const float* lnb = (const float*)d_in[8];

    const size_t tsz = (size_t)BATCH * CH * HWSZ;   // 67,108,864 elements
    if (ws_size < 4 * tsz * sizeof(unsigned short)) return;  // 512 MiB scratch needed

    unsigned short* qh = (unsigned short*)d_ws;
    unsigned short* kh = qh + tsz;
    unsigned short* vh = kh + tsz;
    unsigned short* ob = vh + tsz;

    proj_kernel<<<dim3(HWSZ / 64, BATCH, 3), 256, 0, stream>>>(q, k, v, wq, wk, wvw, qh, kh, vh);
    attn_kernel<<<dim3(64, NHEAD, BATCH), 256, 0, stream>>>(qh, kh, vh, ob);
    fcln_kernel<<<dim3(HWSZ / 64, BATCH, 1), 256, 0, stream>>>(ob, wfc, q, lnw, lnb, (float*)d_out);
}